// Round 7
// baseline (4731.668 us; speedup 1.0000x reference)
//
#include <hip/hip_runtime.h>
#include <cstdint>

#define NS 2048      // states S
#define NE 65536     // arcs E
#define ND 2048      // pdfs D
#define NB 32        // batch
#define NT 500       // frames
#define NGROUPS 32   // 64-state dest groups
#define ELLCAP (2*NE)   // uint4 entries; padded total ~102K < 131072
#define LEAKYF 0.1f
#define NBG 16       // batch groups (2 batches each)
#define NSP 32       // state partitions (64 states each) -> 512 WGs, 2 per CU

// ws byte offsets
#define WS_COUNTS 0
#define WS_CURSOR 8192
#define WS_WIDTHS 16384
#define WS_GBASE  16640
#define WS_BARCNT 16896      // 16 bg x 128B line
#define WS_ALBUF  20480      // 2 par x 16 bg x 2048 x 8B = 512 KB
#define WS_ARC    544768     // ELLCAP * 16B = 2 MB

// ---- per-op device-coherent (L3) access, NO cache-wide fences ----
__device__ __forceinline__ void st_pair2(float2* p, float2 v) {
    union { float f[2]; unsigned long long u; } q; q.f[0] = v.x; q.f[1] = v.y;
    __hip_atomic_store(reinterpret_cast<unsigned long long*>(p), q.u,
                       __ATOMIC_RELAXED, __HIP_MEMORY_SCOPE_AGENT);
}
__device__ __forceinline__ float2 ld_pair2(const float2* p) {
    unsigned long long u = __hip_atomic_load(
        reinterpret_cast<const unsigned long long*>(p),
        __ATOMIC_RELAXED, __HIP_MEMORY_SCOPE_AGENT);
    union { unsigned long long u; float f[2]; } q; q.u = u;
    return make_float2(q.f[0], q.f[1]);
}

__global__ void k_init(const float* __restrict__ log_init, float* albuf,
                       uint32_t* counts, uint32_t* cursor, uint4* arcp,
                       uint32_t* barcnt, float* out) {
    int tid = blockIdx.x * blockDim.x + threadIdx.x;
    int n = blockDim.x * gridDim.x;
    for (int i = tid; i < NS; i += n) { counts[i] = 0u; cursor[i] = 0u; }
    for (int i = tid; i < ELLCAP; i += n) arcp[i] = make_uint4(0u, 0u, 0u, 0u);
    for (int i = tid; i < NBG * NS; i += n) {
        int s = i & (NS - 1);
        float a = __expf(log_init[s]);
        reinterpret_cast<float2*>(albuf)[i] = make_float2(a, a);  // parity0: [bg][s]
    }
    for (int i = tid; i < NBG * 32; i += n) barcnt[i] = 0u;
    if (tid == 0) out[0] = 0.0f;
}

__global__ void k_count(const int* __restrict__ to_state, uint32_t* counts) {
    int e = blockIdx.x * blockDim.x + threadIdx.x;
    if (e < NE) atomicAdd(&counts[to_state[e]], 1u);
}

__global__ void k_widths(const uint32_t* __restrict__ counts, uint32_t* widths, uint32_t* gbase) {
    int g = threadIdx.x;
    if (g < NGROUPS) {
        uint32_t w = 0u;
        for (int i = 0; i < 64; ++i) w = max(w, counts[g*64 + i]);
        widths[g] = w;
    }
    __syncthreads();
    if (threadIdx.x == 0) {
        uint32_t acc = 0u;
        for (int g2 = 0; g2 < NGROUPS; ++g2) { gbase[g2] = acc; acc += widths[g2] * 64u; }
        gbase[NGROUPS] = acc;
    }
}

__global__ void k_scatter(const int* __restrict__ from_state, const int* __restrict__ to_state,
                          const int* __restrict__ pdf_ids, const float* __restrict__ log_w,
                          const float* __restrict__ log_init,
                          const uint32_t* __restrict__ gbase, uint32_t* cursor, uint4* arcp) {
    int e = blockIdx.x * blockDim.x + threadIdx.x;
    if (e >= NE) return;
    int s = to_state[e];
    int g = s >> 6;
    uint32_t slot = atomicAdd(&cursor[s], 1u);
    uint32_t pos = gbase[g] + slot * 64u + (uint32_t)(s & 63);
    int fs = from_state[e];
    uint32_t meta = (uint32_t)fs | ((uint32_t)pdf_ids[e] << 16);
    float w  = __expf(log_w[e]);
    float w2 = LEAKYF * __expf(log_init[fs]) * w;   // leaky-path weight
    arcp[pos] = make_uint4(meta, __float_as_uint(w), __float_as_uint(w2), 0u);
}

// 512 persistent WGs (2 per CU): decode keeps every WG of a bg on XCD bg%8,
// and the two WGs co-resident on a CU serve DIFFERENT batch-groups (bg, bg+8)
// so sync latency of one hides under the other's compute.
__global__ __launch_bounds__(1024, 8) void k_fwd(
    const float* __restrict__ x, const float* __restrict__ log_final,
    const uint4* __restrict__ arc, const uint32_t* __restrict__ widths,
    const uint32_t* __restrict__ gbase,
    float* __restrict__ albuf, uint32_t* __restrict__ barcnt, float* out)
{
    __shared__ __align__(16) float2 e2[NS];        // 16 KB raw alpha
    __shared__ __align__(16) float2 Xs[2][ND];     // 32 KB exp(x) double-buffered
    __shared__ __align__(16) float2 pt1[16][64];   // 8 KB main partials
    __shared__ __align__(16) float2 pt2[16][64];   // 8 KB leaky partials
    __shared__ __align__(16) float2 red[16];

    const int tid  = threadIdx.x;
    const int bid  = blockIdx.x;
    const int b8   = (bid >> 8) & 1;
    const int bg   = ((bid & 15) + (b8 << 3)) & 15;
    const int sp   = ((bid >> 4) & 15) | (b8 << 4);
    const int lane = tid & 63;
    const int wid  = tid >> 6;
    const int g    = sp;                 // my single 64-state dest group

    const float* x0 = x + (size_t)(bg * 2)     * NT * ND;
    const float* x1 = x + (size_t)(bg * 2 + 1) * NT * ND;

    // Xs[0] prologue (read after (B)+(B2) of t=0)
    Xs[0][tid]        = make_float2(__expf(x0[tid]),        __expf(x1[tid]));
    Xs[0][tid + 1024] = make_float2(__expf(x0[tid + 1024]), __expf(x1[tid + 1024]));

    const int wd = (int)widths[g];
    const uint4* ap = arc + gbase[g] + lane;     // slot i at ap[i*64]
    uint32_t* mycnt = barcnt + bg * 32;          // one 128B line per batch-group

    float C0 = 0.f, C1 = 0.f;

    for (int t = 0; t < NT; ++t) {
        const int par = t & 1;
        const float2* cbuf = reinterpret_cast<const float2*>(albuf)
                             + ((size_t)par * NBG + bg) * NS;
        float2* nbuf = reinterpret_cast<float2*>(albuf)
                       + ((size_t)(par ^ 1) * NBG + bg) * NS;

        // x(t+1) prefetch into regs (independent of the handoff)
        float pa0, pa1, pb0, pb1;
        const bool pf = (t + 1 < NT);
        if (pf) {
            const size_t o = (size_t)(t + 1) * ND;
            pa0 = x0[o + tid];        pb0 = x1[o + tid];
            pa1 = x0[o + tid + 1024]; pb1 = x1[o + tid + 1024];
        }

        __syncthreads();   // (B): wave0 finished spin(t-1) -> albuf[par] readable

        // raw alpha -> LDS + wave partials of total mass
        float2 A0 = ld_pair2(cbuf + tid);
        float2 A1 = ld_pair2(cbuf + tid + 1024);
        e2[tid]        = A0;
        e2[tid + 1024] = A1;
        float u0 = A0.x + A1.x, u1 = A0.y + A1.y;
        #pragma unroll
        for (int off = 32; off > 0; off >>= 1) {
            u0 += __shfl_down(u0, off, 64);
            u1 += __shfl_down(u1, off, 64);
        }
        if (lane == 0) red[wid] = make_float2(u0, u1);
        __syncthreads();   // (B2): e2 + red + Xs[par] ready

        // arc pass on RAW alpha: s1 = sum a[src]*w*X ; s2 = sum w2*X
        float2 s1 = make_float2(0.f, 0.f);
        float2 s2 = make_float2(0.f, 0.f);
        for (int i = wid; i < wd; i += 16) {
            uint4 A = ap[(size_t)i * 64];
            const float w  = __uint_as_float(A.y);
            const float w2 = __uint_as_float(A.z);
            const int src = (int)(A.x & 0xFFFFu);
            const int pdf = (int)(A.x >> 16);
            float2 ev = e2[src];
            float2 xv = Xs[par][pdf];
            s1.x += ev.x * (w * xv.x);
            s1.y += ev.y * (w * xv.y);
            s2.x += w2 * xv.x;
            s2.y += w2 * xv.y;
        }
        pt1[wid][lane] = s1;
        pt2[wid][lane] = s2;
        if (pf) {   // exp into the other Xs buffer
            Xs[par ^ 1][tid]        = make_float2(__expf(pa0), __expf(pb0));
            Xs[par ^ 1][tid + 1024] = make_float2(__expf(pa1), __expf(pb1));
        }
        __syncthreads();   // (C): pt ready

        // wave-0 tail: reduce 16 wave-partials, scale by invT, store 64 states,
        // release (vmcnt), arrive, spin. Other waves run ahead to (B) of t+1.
        if (wid == 0) {
            float2 r1 = pt1[0][lane], r2 = pt2[0][lane];
            #pragma unroll
            for (int k = 1; k < 16; ++k) {
                float2 q;
                q = pt1[k][lane]; r1.x += q.x; r1.y += q.y;
                q = pt2[k][lane]; r2.x += q.x; r2.y += q.y;
            }
            float T0 = 0.f, T1 = 0.f;
            #pragma unroll
            for (int j = 0; j < 16; ++j) { float2 q = red[j]; T0 += q.x; T1 += q.y; }
            const float i0 = 1.0f / T0, i1 = 1.0f / T1;
            C0 += __logf(T0); C1 += __logf(T1);
            st_pair2(nbuf + sp * 64 + lane,
                     make_float2(r1.x * i0 + r2.x, r1.y * i1 + r2.y));
            // wave-scope release: drain coherent store (at L3) -- no cache flush
            asm volatile("s_waitcnt vmcnt(0)" ::: "memory");
            if (lane == 0) {
                __hip_atomic_fetch_add(mycnt, 1u, __ATOMIC_RELAXED,
                                       __HIP_MEMORY_SCOPE_AGENT);
                const uint32_t tgt = 32u * (uint32_t)(t + 1);
                while (__hip_atomic_load(mycnt, __ATOMIC_RELAXED,
                                         __HIP_MEMORY_SCOPE_AGENT) < tgt)
                    __builtin_amdgcn_s_sleep(1);
            }
        }
    }
    __syncthreads();   // all waves gated behind final spin

    // epilogue: sp==0 WG per batch-group; final raw alpha in parity 0 (NT even)
    if (sp == 0) {
        const float2* fbuf = reinterpret_cast<const float2*>(albuf) + (size_t)bg * NS;
        float2 A0 = ld_pair2(fbuf + tid);
        float2 A1 = ld_pair2(fbuf + tid + 1024);
        float f0 = __expf(log_final[tid]);
        float f1 = __expf(log_final[tid + 1024]);
        float u0 = A0.x * f0 + A1.x * f1;
        float u1 = A0.y * f0 + A1.y * f1;
        #pragma unroll
        for (int off = 32; off > 0; off >>= 1) {
            u0 += __shfl_down(u0, off, 64);
            u1 += __shfl_down(u1, off, 64);
        }
        if (lane == 0) red[wid] = make_float2(u0, u1);
        __syncthreads();
        if (tid == 0) {
            float t0 = 0.f, t1 = 0.f;
            #pragma unroll
            for (int j = 0; j < 16; ++j) { t0 += red[j].x; t1 += red[j].y; }
            atomicAdd(out, -(__logf(t0) + C0) - (__logf(t1) + C1));
        }
    }
}

extern "C" void kernel_launch(void* const* d_in, const int* in_sizes, int n_in,
                              void* d_out, int out_size, void* d_ws, size_t ws_size,
                              hipStream_t stream) {
    const float* x         = (const float*)d_in[0];
    const float* log_w     = (const float*)d_in[1];
    const float* log_init  = (const float*)d_in[2];
    const float* log_final = (const float*)d_in[3];
    const int*   from_st   = (const int*)d_in[4];
    const int*   to_st     = (const int*)d_in[5];
    const int*   pdf_ids   = (const int*)d_in[6];
    float* out = (float*)d_out;

    uint8_t* ws = (uint8_t*)d_ws;
    uint32_t* counts = (uint32_t*)(ws + WS_COUNTS);
    uint32_t* cursor = (uint32_t*)(ws + WS_CURSOR);
    uint32_t* widths = (uint32_t*)(ws + WS_WIDTHS);
    uint32_t* gbase  = (uint32_t*)(ws + WS_GBASE);
    uint32_t* barcnt = (uint32_t*)(ws + WS_BARCNT);
    float*    albuf  = (float*)(ws + WS_ALBUF);
    uint4*    arc    = (uint4*)(ws + WS_ARC);

    k_init   <<<512, 256, 0, stream>>>(log_init, albuf, counts, cursor, arc, barcnt, out);
    k_count  <<<NE/256, 256, 0, stream>>>(to_st, counts);
    k_widths <<<1, 64, 0, stream>>>(counts, widths, gbase);
    k_scatter<<<NE/256, 256, 0, stream>>>(from_st, to_st, pdf_ids, log_w, log_init,
                                          gbase, cursor, arc);
    k_fwd    <<<NSP*NBG, 1024, 0, stream>>>(x, log_final, arc, widths, gbase,
                                            albuf, barcnt, out);
}